// Round 1
// 603.257 us; speedup vs baseline: 1.0323x; 1.0323x over previous
//
#include <hip/hip_runtime.h>
#include <stdint.h>
#include <stddef.h>

// ---------------------------------------------------------------------------
// out[b,t,f] = x @ (w + 2.0 * lora_a @ lora_b)     (LoRA folded into weight)
// M = 8192 (B*T), K = 2048 (D), N = 8192 (F). fp32 in/out, bf16 MFMA compute.
// GEMM: 256x256 8-phase counted-vmcnt schedule (T1+T2+T3+T4+T5).
// ---------------------------------------------------------------------------

typedef __bf16 bf16;
typedef __bf16 bf16x4 __attribute__((ext_vector_type(4)));
typedef __bf16 bf16x8 __attribute__((ext_vector_type(8)));
typedef float  f32x4  __attribute__((ext_vector_type(4)));

#define M_DIM 8192
#define N_DIM 8192
#define K_DIM 2048
#define LRANK 16
#define LSCALE 2.0f

#define BM 256
#define BN 256
#define BK 64
#define NT (K_DIM / BK)          // 32 K-tiles, 16 iterations of 2

typedef __attribute__((address_space(1))) void* as1_void;
typedef __attribute__((address_space(3))) void* as3_void;

__device__ __forceinline__ void gload_lds16(const void* g, void* l) {
    // async global->LDS, 16 bytes per lane; LDS dst is wave-uniform base + lane*16.
    __builtin_amdgcn_global_load_lds((as1_void)(g), (as3_void)(l), 16, 0, 0);
}

// ---------------------------------------------------------------------------
// Kernel 1: x fp32 -> bf16, straight convert. 4 elems/thread.
// ---------------------------------------------------------------------------
__global__ void convert_x_kernel(const float* __restrict__ x,
                                 bf16* __restrict__ xb) {
    int i = (blockIdx.x * blockDim.x + threadIdx.x) * 4;
    float4 v = *(const float4*)(x + i);
    bf16x4 o;
    o.x = (bf16)v.x; o.y = (bf16)v.y; o.z = (bf16)v.z; o.w = (bf16)v.w;
    *(bf16x4*)(xb + i) = o;
}

// ---------------------------------------------------------------------------
// Kernel 2: Wt[n][k] = bf16( w[k][n] + 2.0 * sum_L a[k][L]*b[L][n] )
// 32x32 tile transpose through LDS; coalesced loads AND stores.
// ---------------------------------------------------------------------------
__global__ void fold_transpose_kernel(const float* __restrict__ w,   // [K][N]
                                      const float* __restrict__ la,  // [K][16]
                                      const float* __restrict__ lb,  // [16][N]
                                      bf16* __restrict__ wt) {       // [N][K]
    __shared__ float tile[32][33];
    __shared__ float at[32][17];
    __shared__ float bt[16][32];

    const int k0 = blockIdx.x * 32;
    const int n0 = blockIdx.y * 32;
    const int t  = threadIdx.x;      // 256 threads
    const int c  = t & 31;
    const int r0 = t >> 5;           // 0..7

    #pragma unroll
    for (int rr = 0; rr < 32; rr += 8)
        tile[r0 + rr][c] = w[(size_t)(k0 + r0 + rr) * N_DIM + n0 + c];

    at[t >> 4][t & 15]          = la[(size_t)(k0 + (t >> 4)) * LRANK + (t & 15)];
    at[(t + 256) >> 4][t & 15]  = la[(size_t)(k0 + ((t + 256) >> 4)) * LRANK + (t & 15)];

    bt[t >> 5][c]       = lb[(size_t)(t >> 5) * N_DIM + n0 + c];
    bt[(t >> 5) + 8][c] = lb[(size_t)((t >> 5) + 8) * N_DIM + n0 + c];

    __syncthreads();

    #pragma unroll
    for (int rr = 0; rr < 32; rr += 8) {
        const int nl = r0 + rr;
        const int kl = c;
        float delta = 0.f;
        #pragma unroll
        for (int L = 0; L < LRANK; ++L)
            delta += at[kl][L] * bt[L][nl];
        float v = tile[kl][nl] + LSCALE * delta;
        wt[(size_t)(n0 + nl) * K_DIM + k0 + kl] = (bf16)v;
    }
}

// ---------------------------------------------------------------------------
// Kernel 3: C[M][N] = A[M][K] * Bt[N][K]^T  — 256x256 tile, 8-phase schedule.
//
// 8 waves, 2(M)x4(N). Wave output is interleaved so quadrants map to halves:
//   wave_m owns rows  wm + [0,64)      (A-half0)  and  128+wm + [0,64)  (A-half1)
//   wave_n owns cols  wn + [0,32)      (B-half0)  and  128+wn + [0,32)  (B-half1)
// Phase quadrants: Q1=A0xB0, Q2=A0xB1, Q3=A1xB0, Q4=A1xB1 -> each LDS half's
// last reader is ordered, so each phase stages exactly one half-tile and the
// only vmem waits are vmcnt(4) at phases 4 and 8 (never 0 in the main loop).
//
// Stage schedule per iteration (tiles t=2i in buf0, t+1 in buf1):
//   P1: A1(t+1)->buf1   P2: B1(t+1)->buf1   P3: A0(t+2)->buf0
//   P4: B0(t+2)->buf0 +vmcnt(4)             P5: A1(t+2)->buf0
//   P6: B1(t+2)->buf0   P7: A0(t+3)->buf1   P8: B0(t+3)->buf1 +vmcnt(4)
// vmcnt(4) leaves the 2 youngest half-tiles (4 loads) in flight and certifies
// the 4 halves the next 4 phases read. WAR: every stage lands >=1 phase after
// its region's last ds_read (verified per-phase).  Tail stages clamp to tile
// NT-1 (re-writes identical bytes into a dead or same-data region — benign).
// ---------------------------------------------------------------------------

#define BAR()   __builtin_amdgcn_s_barrier()
#define WAITL() do { asm volatile("s_waitcnt lgkmcnt(0)" ::: "memory"); \
                     __builtin_amdgcn_sched_barrier(0); } while (0)
#define WAITV4() asm volatile("s_waitcnt vmcnt(4)" ::: "memory")
#define PRHI()  __builtin_amdgcn_s_setprio(1)
#define PRLO()  __builtin_amdgcn_s_setprio(0)

#define STAGE_A(t, h, buf) do {                                                   \
    _Pragma("unroll")                                                             \
    for (int c_ = 0; c_ < 2; ++c_)                                                \
        gload_lds16(aG + (size_t)((h) * 128 + prow[c_]) * K_DIM + (t) * BK + pcl[c_] * 8, \
                    As + (buf) * (BM * BK) + (h) * 8192 + c_ * 4096 + tid * 8);   \
} while (0)

#define STAGE_B(t, h, buf) do {                                                   \
    _Pragma("unroll")                                                             \
    for (int c_ = 0; c_ < 2; ++c_)                                                \
        gload_lds16(bG + (size_t)((h) * 128 + prow[c_]) * K_DIM + (t) * BK + pcl[c_] * 8, \
                    Bs + (buf) * (BN * BK) + (h) * 8192 + c_ * 4096 + tid * 8);   \
} while (0)

#define RD_A(grp, buf) do {                                                       \
    _Pragma("unroll")                                                             \
    for (int q_ = 0; q_ < 4; ++q_) {                                              \
        af[q_][0] = *(const bf16x8*)(As + (buf) * (BM * BK) + baseA[(grp) + q_]); \
        af[q_][1] = *(const bf16x8*)(As + (buf) * (BM * BK) + (baseA[(grp) + q_] ^ 32)); \
    }                                                                             \
} while (0)

#define RD_B(dst, jlo, buf) do {                                                  \
    _Pragma("unroll")                                                             \
    for (int q_ = 0; q_ < 2; ++q_) {                                              \
        dst[q_][0] = *(const bf16x8*)(Bs + (buf) * (BN * BK) + baseB[(jlo) + q_]);\
        dst[q_][1] = *(const bf16x8*)(Bs + (buf) * (BN * BK) + (baseB[(jlo) + q_] ^ 32)); \
    }                                                                             \
} while (0)

#define MMQ(I0, J0, BF) do {                                                      \
    _Pragma("unroll")                                                             \
    for (int q_ = 0; q_ < 4; ++q_)                                                \
        _Pragma("unroll")                                                         \
        for (int jj_ = 0; jj_ < 2; ++jj_)                                         \
            _Pragma("unroll")                                                     \
            for (int ks_ = 0; ks_ < 2; ++ks_)                                     \
                acc[(I0) + q_][(J0) + jj_] = __builtin_amdgcn_mfma_f32_16x16x32_bf16( \
                    af[q_][ks_], BF[jj_][ks_], acc[(I0) + q_][(J0) + jj_], 0, 0, 0);  \
} while (0)

__global__ __launch_bounds__(512, 2)
void gemm_bf16_kernel(const bf16* __restrict__ A,   // [M][K]
                      const bf16* __restrict__ Bt,  // [N][K]
                      float* __restrict__ C) {      // [M][N]
    __shared__ __align__(16) bf16 As[2 * BM * BK];  // 64 KB (2 bufs x 256x64)
    __shared__ __align__(16) bf16 Bs[2 * BN * BK];  // 64 KB

    const int tid  = threadIdx.x;        // 0..511
    const int lane = tid & 63;
    const int wave = tid >> 6;           // 0..7
    const int wm   = (wave >> 2) * 64;   // 0 / 64
    const int wn   = (wave & 3) * 32;    // 0 / 32 / 64 / 96

    // T1: XCD-aware swizzle over the 32x32 block grid (1024 % 8 == 0)
    const int id  = blockIdx.y * 32 + blockIdx.x;
    const int swz = (id & 7) * 128 + (id >> 3);
    const int m0  = (swz >> 5) * BM;
    const int n0  = (swz & 31) * BN;

    // staging descriptors: physical chunk cp at (row,cp) holds k-chunk cp^(row&7)
    int prow[2], pcl[2];
    #pragma unroll
    for (int c = 0; c < 2; ++c) {
        int p   = c * 8192 + tid * 16;   // byte pos within a 16 KB half-tile
        prow[c] = p >> 7;                // 128 B per row
        pcl[c]  = ((p >> 4) & 7) ^ (prow[c] & 7);
    }
    const bf16* aG = A  + (size_t)m0 * K_DIM;
    const bf16* bG = Bt + (size_t)n0 * K_DIM;

    // fragment base offsets (ks=0); ks toggles elem-bit5 (XOR 32)
    int baseA[8], baseB[4];
    #pragma unroll
    for (int i = 0; i < 8; ++i) {
        int ra = ((i & 4) ? 128 : 0) + wm + (i & 3) * 16 + (lane & 15);
        baseA[i] = ra * 64 + (((lane >> 4) ^ (ra & 7)) * 8);
    }
    #pragma unroll
    for (int j = 0; j < 4; ++j) {
        int rb = ((j & 2) ? 128 : 0) + wn + (j & 1) * 16 + (lane & 15);
        baseB[j] = rb * 64 + (((lane >> 4) ^ (rb & 7)) * 8);
    }

    f32x4 acc[8][4] = {};
    bf16x8 af[4][2], bA[2][2], bBv[2][2];

    // prologue: issue order must match steady-state tail: A0(0) B0(0) A1(0) B1(0) A0(1) B0(1)
    STAGE_A(0, 0, 0); STAGE_B(0, 0, 0);
    STAGE_A(0, 1, 0); STAGE_B(0, 1, 0);
    STAGE_A(1, 0, 1); STAGE_B(1, 0, 1);
    WAITV4();   // oldest 8 loads (= all of tile 0) landed; tile1 A0/B0 stay in flight
    BAR();

    for (int it = 0; it < NT / 2; ++it) {
        const int t1 = 2 * it + 1;
        const int t2 = (2 * it + 2 < NT) ? 2 * it + 2 : NT - 1;
        const int t3 = (2 * it + 3 < NT) ? 2 * it + 3 : NT - 1;

        // ---------------- tile 2it from buf0 ----------------
        // P1: Q1 = A0 x B0
        RD_A(0, 0); RD_B(bA, 0, 0);
        STAGE_A(t1, 1, 1);
        BAR(); WAITL(); PRHI(); MMQ(0, 0, bA); PRLO(); BAR();
        // P2: Q2 = A0 x B1
        RD_B(bBv, 2, 0);
        STAGE_B(t1, 1, 1);
        BAR(); WAITL(); PRHI(); MMQ(0, 2, bBv); PRLO(); BAR();
        // P3: Q3 = A1 x B0
        RD_A(4, 0);
        STAGE_A(t2, 0, 0);
        BAR(); WAITL(); PRHI(); MMQ(4, 0, bA); PRLO(); BAR();
        // P4: Q4 = A1 x B1 (no new ds_reads)
        STAGE_B(t2, 0, 0);
        WAITV4();    // certifies all 4 halves of tile 2it+1
        BAR(); PRHI(); MMQ(4, 2, bBv); PRLO(); BAR();

        // ---------------- tile 2it+1 from buf1 ----------------
        // P5: Q1
        RD_A(0, 1); RD_B(bA, 0, 1);
        STAGE_A(t2, 1, 0);
        BAR(); WAITL(); PRHI(); MMQ(0, 0, bA); PRLO(); BAR();
        // P6: Q2
        RD_B(bBv, 2, 1);
        STAGE_B(t2, 1, 0);
        BAR(); WAITL(); PRHI(); MMQ(0, 2, bBv); PRLO(); BAR();
        // P7: Q3
        RD_A(4, 1);
        STAGE_A(t3, 0, 1);
        BAR(); WAITL(); PRHI(); MMQ(4, 0, bA); PRLO(); BAR();
        // P8: Q4
        STAGE_B(t3, 0, 1);
        WAITV4();    // certifies all 4 halves of tile 2it+2
        BAR(); PRHI(); MMQ(4, 2, bBv); PRLO(); BAR();
    }

    // epilogue: C/D layout col = lane&15, row = (lane>>4)*4 + reg
    const int cr = (lane >> 4) * 4;
    const int cc = lane & 15;
    #pragma unroll
    for (int i = 0; i < 8; ++i) {
        const int row = m0 + ((i & 4) ? 128 : 0) + wm + (i & 3) * 16 + cr;
        #pragma unroll
        for (int j = 0; j < 4; ++j) {
            const int col = n0 + ((j & 2) ? 128 : 0) + wn + (j & 1) * 16 + cc;
            float* cp = C + (size_t)row * N_DIM + col;
            #pragma unroll
            for (int r = 0; r < 4; ++r)
                cp[(size_t)r * N_DIM] = acc[i][j][r];
        }
    }
}

// ---------------------------------------------------------------------------
extern "C" void kernel_launch(void* const* d_in, const int* in_sizes, int n_in,
                              void* d_out, int out_size, void* d_ws, size_t ws_size,
                              hipStream_t stream) {
    const float* x  = (const float*)d_in[0];   // [B,T,D] = [8192, 2048]
    const float* w  = (const float*)d_in[1];   // [D, F]  = [2048, 8192]
    const float* la = (const float*)d_in[2];   // [D, 16]
    const float* lb = (const float*)d_in[3];   // [16, F]
    float* out = (float*)d_out;                // [8192, 8192]

    bf16* xb = (bf16*)d_ws;                                        // 32 MB
    bf16* wt = (bf16*)((char*)d_ws + (size_t)M_DIM * K_DIM * 2);   // 32 MB

    convert_x_kernel<<<M_DIM * K_DIM / 4 / 256, 256, 0, stream>>>(x, xb);
    fold_transpose_kernel<<<dim3(K_DIM / 32, N_DIM / 32), 256, 0, stream>>>(w, la, lb, wt);
    gemm_bf16_kernel<<<dim3(N_DIM / BN, M_DIM / BM), 512, 0, stream>>>(xb, wt, out);
}